// Round 8
// baseline (331.643 us; speedup 1.0000x reference)
//
#include <hip/hip_runtime.h>

#define COLS    32768
#define COLS4   8192
#define KSEL    32
#define BAR     2.5f
#define NT      256
#define GRID1   2048      // dense sweep: 8 blocks/CU, m13 copy-ubench shape
#define LCAP    1024      // per-block LDS candidate cap (expected ~406, 30 sigma)
#define GCAP    480       // per-row global candidate cap (expected ~203, 19 sigma)
#define CAPF    512       // fallback LDS cap
#define REF_CAP 256

typedef float f32x4 __attribute__((ext_vector_type(4)));

// Pipeline key: [bits:32 | (32767-idx):15 | row:12]  (59 bits)
// Within a row (equal low 12 bits), bigger key == bigger value, ties to
// smaller index — matches jax.lax.top_k order. All keys distinct.
__device__ __forceinline__ unsigned long long mk_key3(float v, int row, int idx) {
    return ((unsigned long long)__float_as_uint(v) << 27)
         | ((unsigned long long)(32767 - idx) << 12)
         | (unsigned)row;
}
// Row-local key for fallback paths: [bits:32 | (0xFFFF-idx):16]
__device__ __forceinline__ unsigned long long mk_key(float v, int idx) {
    return ((unsigned long long)__float_as_uint(v) << 32) | (unsigned)(0xFFFF - idx);
}

// ---- K1: dense grid-stride sweep (copy-ubench pattern). Cacheable x reads
// (L3 serves ~half across replays), NT zero-stores to out, rare candidate
// push to block-local LDS; one amortized flush to per-row buffers at end. ----
__global__ __launch_bounds__(NT) void sweep_kernel(
        const float* __restrict__ x, float* __restrict__ out,
        unsigned long long* __restrict__ gcand, int* __restrict__ gcnt,
        int* __restrict__ gflag, int nv4) {
    __shared__ unsigned long long lc[LCAP];
    __shared__ int lcnt;
    if (threadIdx.x == 0) lcnt = 0;
    __syncthreads();

    const f32x4* __restrict__ x4 = (const f32x4*)x;
    f32x4* __restrict__ o4 = (f32x4*)out;
    const int stride = GRID1 * NT;
    const f32x4 z = 0;

#pragma unroll 4
    for (int g = blockIdx.x * NT + threadIdx.x; g < nv4; g += stride) {
        const f32x4 v = x4[g];
        __builtin_nontemporal_store(z, o4 + g);
        const float m = fmaxf(fmaxf(v.x, v.y), fmaxf(v.z, v.w));
        if (m > BAR) {                       // ~0.6% of lanes
            const int row = g >> 13;
            const int bi = (g & (COLS4 - 1)) * 4;
            if (v.x > BAR) { int p = atomicAdd(&lcnt, 1); if (p < LCAP) lc[p] = mk_key3(v.x, row, bi + 0); }
            if (v.y > BAR) { int p = atomicAdd(&lcnt, 1); if (p < LCAP) lc[p] = mk_key3(v.y, row, bi + 1); }
            if (v.z > BAR) { int p = atomicAdd(&lcnt, 1); if (p < LCAP) lc[p] = mk_key3(v.z, row, bi + 2); }
            if (v.w > BAR) { int p = atomicAdd(&lcnt, 1); if (p < LCAP) lc[p] = mk_key3(v.w, row, bi + 3); }
        }
    }
    __syncthreads();
    int n = lcnt;
    if (n > LCAP) {                          // dropped candidates: force global fallback
        if (threadIdx.x == 0) atomicOr(gflag, 1);
        n = LCAP;
    }
    // amortized flush: ~406 keys spread over ~64 distinct rows
    for (int c = threadIdx.x; c < n; c += NT) {
        const unsigned long long k = lc[c];
        const int row = (int)(k & 0xFFFu);
        const int p = atomicAdd(&gcnt[row], 1);
        if (p < GCAP) gcand[(size_t)row * GCAP + p] = k;
    }
}

// ---- K2: per-row select + scatter. out already zeroed by K1. ----
__global__ __launch_bounds__(NT) void select_kernel(
        const float* __restrict__ x, float* __restrict__ out,
        const unsigned long long* __restrict__ gcand, const int* __restrict__ gcnt,
        const int* __restrict__ gflag) {
    __shared__ unsigned long long cand[CAPF];
    __shared__ unsigned hist[256];
    __shared__ int s_cnt, s_bstar, s_cum;

    const int tid = threadIdx.x;
    const int row = blockIdx.x;
    float* __restrict__ outr = out + (size_t)row * COLS;
    const int N = gcnt[row];

    if (*gflag == 0 && N >= KSEL && N <= GCAP) {
        // common path: stage this row's candidates, direct O(N^2) rank-select
        const unsigned long long* __restrict__ gr = gcand + (size_t)row * GCAP;
        for (int c = tid; c < N; c += NT) cand[c] = gr[c];
        __syncthreads();
        for (int c = tid; c < N; c += NT) {
            const unsigned long long kc = cand[c];
            int rank = 0;
            for (int j = 0; j < N; ++j) rank += (cand[j] > kc) ? 1 : 0;
            if (rank < KSEL)      // all candidates > BAR > 0: no ReLU filtering needed
                outr[32767 - (int)((kc >> 12) & 0x7FFFu)] = __uint_as_float((unsigned)(kc >> 27));
        }
        return;
    }

    // ---- exact fallback (N<K, overflow, or global flag; never on N(0,1)):
    // radix select re-reading the (L3-warm) row. ----
    const float* __restrict__ xr = x + (size_t)row * COLS;
    unsigned pref = 0, thr = 1;
    int need = KSEL, above = 0;
    for (int s = 24; s >= 0; s -= 8) {
        __syncthreads();
        hist[tid] = 0;
        __syncthreads();
        for (int i = tid; i < COLS; i += NT) {
            float v = xr[i];
            if (v > 0.f) {
                unsigned bits = __float_as_uint(v);
                if (s == 24 || (bits >> (s + 8)) == pref)
                    atomicAdd(&hist[(bits >> s) & 255u], 1u);
            }
        }
        __syncthreads();
        if (tid == 0) {
            int cum = 0, b = 255;
            for (; b >= 0; --b) { if (cum + (int)hist[b] >= need) break; cum += (int)hist[b]; }
            s_bstar = b; s_cum = cum;
        }
        __syncthreads();
        const int b = s_bstar, cum = s_cum;
        if (b < 0) { thr = 1; break; }   // fewer than K positives: take all positives
        above += cum;
        need -= cum;
        pref = (pref << 8) | (unsigned)b;
        thr = pref << s;
        const int total = above + (int)hist[b];
        if (total <= CAPF || s == 0) break;
    }
    __syncthreads();
    if (tid == 0) s_cnt = 0;
    __syncthreads();
    for (int i = tid; i < COLS; i += NT) {
        float v = xr[i];
        if (v > 0.f) {
            unsigned bits = __float_as_uint(v);
            if (bits >= thr) {
                int p = atomicAdd(&s_cnt, 1);
                if (p < CAPF) cand[p] = mk_key(v, i);
            }
        }
    }
    __syncthreads();
    const int M2 = min(s_cnt, CAPF);
    for (int c = tid; c < M2; c += NT) {
        const unsigned long long kc = cand[c];
        int rank = 0;
        for (int j = 0; j < M2; ++j) rank += (cand[j] > kc) ? 1 : 0;
        if (rank < KSEL)
            outr[0xFFFF - (int)(kc & 0xFFFFu)] = __uint_as_float((unsigned)(kc >> 32));
    }
}

// ---- fused single-kernel fallback (only if ws too small / rows > 4096) ----
__global__ __launch_bounds__(NT, 8) void topk_fused_kernel(const float* __restrict__ x,
                                                           float* __restrict__ out) {
    __shared__ unsigned long long cand[CAPF];
    __shared__ unsigned long long refbuf[REF_CAP];
    __shared__ unsigned hist[256];
    __shared__ int s_cnt, s_bstar, s_rcnt, s_cum;

    const int tid = threadIdx.x;
    const size_t row = blockIdx.x;
    const float* __restrict__ xr = x + row * COLS;
    float* __restrict__ outr = out + row * COLS;

    if (tid == 0) { s_cnt = 0; s_rcnt = 0; }
    __syncthreads();

    const f32x4* __restrict__ xr4 = (const f32x4*)xr;
    f32x4* __restrict__ our4 = (f32x4*)outr;
#pragma unroll 4
    for (int i = 0; i < COLS / 4 / NT; ++i) {
        const int e = i * NT + tid;
        f32x4 v = __builtin_nontemporal_load(xr4 + e);
        f32x4 z = 0;
        __builtin_nontemporal_store(z, our4 + e);
        const float m = fmaxf(fmaxf(v.x, v.y), fmaxf(v.z, v.w));
        if (m > BAR) {
            const int bi = e * 4;
            if (v.x > BAR) { int p = atomicAdd(&s_cnt, 1); if (p < CAPF) cand[p] = mk_key(v.x, bi + 0); }
            if (v.y > BAR) { int p = atomicAdd(&s_cnt, 1); if (p < CAPF) cand[p] = mk_key(v.y, bi + 1); }
            if (v.z > BAR) { int p = atomicAdd(&s_cnt, 1); if (p < CAPF) cand[p] = mk_key(v.z, bi + 2); }
            if (v.w > BAR) { int p = atomicAdd(&s_cnt, 1); if (p < CAPF) cand[p] = mk_key(v.w, bi + 3); }
        }
    }
    __syncthreads();
    const int N = s_cnt;

    if (N >= KSEL && N <= CAPF) {
        hist[tid] = 0;
        __syncthreads();
        for (int c = tid; c < N; c += NT) {
            unsigned bits = (unsigned)(cand[c] >> 32);
            unsigned b16 = (bits >> 16) - 0x4000u;
            if (b16 > 255u) b16 = 255u;
            atomicAdd(&hist[b16], 1u);
        }
        __syncthreads();
        if (tid < 64) {
            const int lane = tid;
            const unsigned h0 = hist[4 * lane + 0], h1 = hist[4 * lane + 1];
            const unsigned h2 = hist[4 * lane + 2], h3 = hist[4 * lane + 3];
            const unsigned s3 = h3, s2 = h2 + s3, s1 = h1 + s2, s0 = h0 + s1;
            unsigned acc = s0;
#pragma unroll
            for (int off = 1; off < 64; off <<= 1) {
                unsigned o = __shfl_down(acc, off, 64);
                if (lane + off < 64) acc += o;
            }
            const unsigned above = acc - s0;
            const unsigned suf0 = above + s0, suf1 = above + s1;
            const unsigned suf2 = above + s2, suf3 = above + s3;
            unsigned nxt = __shfl_down(suf0, 1, 64);
            const unsigned suf4 = (lane == 63) ? 0u : nxt;
            if (suf0 >= KSEL && suf1 < KSEL) s_bstar = 4 * lane + 0;
            if (suf1 >= KSEL && suf2 < KSEL) s_bstar = 4 * lane + 1;
            if (suf2 >= KSEL && suf3 < KSEL) s_bstar = 4 * lane + 2;
            if (suf3 >= KSEL && suf4 < KSEL) s_bstar = 4 * lane + 3;
        }
        __syncthreads();
        const int bstar = s_bstar;
        for (int c = tid; c < N; c += NT) {
            const unsigned long long kc = cand[c];
            unsigned bits = (unsigned)(kc >> 32);
            unsigned b16 = (bits >> 16) - 0x4000u;
            if (b16 > 255u) b16 = 255u;
            if ((int)b16 >= bstar) { int p = atomicAdd(&s_rcnt, 1); if (p < REF_CAP) refbuf[p] = kc; }
        }
        __syncthreads();
        const int M = s_rcnt;
        if (M <= REF_CAP) {
            for (int c = tid; c < M; c += NT) {
                const unsigned long long kc = refbuf[c];
                int rank = 0;
                for (int j = 0; j < M; ++j) rank += (refbuf[j] > kc) ? 1 : 0;
                if (rank < KSEL)
                    outr[0xFFFF - (int)(kc & 0xFFFFu)] = __uint_as_float((unsigned)(kc >> 32));
            }
        } else {
            for (int c = tid; c < N; c += NT) {
                const unsigned long long kc = cand[c];
                int rank = 0;
                for (int j = 0; j < N; ++j) rank += (cand[j] > kc) ? 1 : 0;
                if (rank < KSEL)
                    outr[0xFFFF - (int)(kc & 0xFFFFu)] = __uint_as_float((unsigned)(kc >> 32));
            }
        }
        return;
    }

    unsigned pref = 0, thr = 1;
    int need = KSEL, above = 0;
    for (int s = 24; s >= 0; s -= 8) {
        __syncthreads();
        hist[tid] = 0;
        __syncthreads();
        for (int i = tid; i < COLS; i += NT) {
            float v = xr[i];
            if (v > 0.f) {
                unsigned bits = __float_as_uint(v);
                if (s == 24 || (bits >> (s + 8)) == pref)
                    atomicAdd(&hist[(bits >> s) & 255u], 1u);
            }
        }
        __syncthreads();
        if (tid == 0) {
            int cum = 0, b = 255;
            for (; b >= 0; --b) { if (cum + (int)hist[b] >= need) break; cum += (int)hist[b]; }
            s_bstar = b; s_cum = cum;
        }
        __syncthreads();
        const int b = s_bstar, cum = s_cum;
        if (b < 0) { thr = 1; break; }
        above += cum;
        need -= cum;
        pref = (pref << 8) | (unsigned)b;
        thr = pref << s;
        const int total = above + (int)hist[b];
        if (total <= CAPF || s == 0) break;
    }
    __syncthreads();
    if (tid == 0) s_cnt = 0;
    __syncthreads();
    for (int i = tid; i < COLS; i += NT) {
        float v = xr[i];
        if (v > 0.f) {
            unsigned bits = __float_as_uint(v);
            if (bits >= thr) {
                int p = atomicAdd(&s_cnt, 1);
                if (p < CAPF) cand[p] = mk_key(v, i);
            }
        }
    }
    __syncthreads();
    const int M2 = min(s_cnt, CAPF);
    for (int c = tid; c < M2; c += NT) {
        const unsigned long long kc = cand[c];
        int rank = 0;
        for (int j = 0; j < M2; ++j) rank += (cand[j] > kc) ? 1 : 0;
        if (rank < KSEL)
            outr[0xFFFF - (int)(kc & 0xFFFFu)] = __uint_as_float((unsigned)(kc >> 32));
    }
}

extern "C" void kernel_launch(void* const* d_in, const int* in_sizes, int n_in,
                              void* d_out, int out_size, void* d_ws, size_t ws_size,
                              hipStream_t stream) {
    const float* x = (const float*)d_in[0];
    float* out = (float*)d_out;
    const int rows = in_sizes[0] / COLS;
    const int nv4 = in_sizes[0] / 4;

    // ws layout: [gcand: rows*GCAP u64 | gcnt: rows int | gflag: 1 int]
    const size_t gcand_bytes = (size_t)rows * GCAP * sizeof(unsigned long long);
    const size_t need = gcand_bytes + (size_t)rows * sizeof(int) + sizeof(int);

    if (ws_size >= need && rows <= 4096) {
        unsigned long long* gcand = (unsigned long long*)d_ws;
        int* gcnt = (int*)((char*)d_ws + gcand_bytes);
        int* gflag = gcnt + rows;
        hipMemsetAsync(gcnt, 0, (size_t)rows * sizeof(int) + sizeof(int), stream);
        hipLaunchKernelGGL(sweep_kernel, dim3(GRID1), dim3(NT), 0, stream,
                           x, out, gcand, gcnt, gflag, nv4);
        hipLaunchKernelGGL(select_kernel, dim3(rows), dim3(NT), 0, stream,
                           x, out, gcand, gcnt, gflag);
    } else {
        hipLaunchKernelGGL(topk_fused_kernel, dim3(rows), dim3(NT), 0, stream, x, out);
    }
}

// Round 9
// 225.559 us; speedup vs baseline: 1.4703x; 1.4703x over previous
//
#include <hip/hip_runtime.h>

#define COLS    32768
#define KSEL    32
#define CAP     1024      // candidate buffer (expected ~203 hits/row at BAR=2.5, 57 sigma margin)
#define REF_CAP 256       // refined buffer after histogram prune (expected ~34)
#define NT      256
#define BAR     2.5f

typedef float f32x4 __attribute__((ext_vector_type(4)));

// key = (float_bits << 32) | (0xFFFF - idx)
// positive float bits are monotonic in value; low 16 bits break ties so that
// larger key == (larger value, or equal value with smaller index) — matching
// jax.lax.top_k tie order. All keys distinct since idx distinct.
__device__ __forceinline__ unsigned long long mk_key(float v, int idx) {
    return ((unsigned long long)__float_as_uint(v) << 32) | (unsigned)(0xFFFF - idx);
}

__global__ __launch_bounds__(NT, 8) void topk_scatter_kernel(const float* __restrict__ x,
                                                             float* __restrict__ out) {
    __shared__ unsigned long long cand[CAP];
    __shared__ unsigned long long refbuf[REF_CAP];
    __shared__ unsigned hist[256];
    __shared__ int s_cnt, s_bstar, s_rcnt, s_cum;

    const int tid = threadIdx.x;
    const size_t row = blockIdx.x;
    const float* __restrict__ xr = x + row * COLS;
    float* __restrict__ outr = out + row * COLS;

    if (tid == 0) { s_cnt = 0; s_rcnt = 0; }
    __syncthreads();

    // ---- Pass 1: stream row. CACHEABLE x loads (L3 holds ~half of x warm
    // across replays: R5/R8 FETCH=262MB), NT zero-stores (write-around keeps
    // L3 for x), rare (0.6%/lane) per-lane LDS push guarded by max4. ----
    const f32x4* __restrict__ xr4 = (const f32x4*)xr;
    f32x4* __restrict__ our4 = (f32x4*)outr;

#pragma unroll 4
    for (int i = 0; i < COLS / 4 / NT; ++i) {
        const int e = i * NT + tid;
        const f32x4 v = xr4[e];                  // cacheable (only change vs R3)
        f32x4 z = 0;
        __builtin_nontemporal_store(z, our4 + e);
        const float m = fmaxf(fmaxf(v.x, v.y), fmaxf(v.z, v.w));
        if (m > BAR) {                       // ~1.6 active lanes when taken
            const int bi = e * 4;
            if (v.x > BAR) { int p = atomicAdd(&s_cnt, 1); if (p < CAP) cand[p] = mk_key(v.x, bi + 0); }
            if (v.y > BAR) { int p = atomicAdd(&s_cnt, 1); if (p < CAP) cand[p] = mk_key(v.y, bi + 1); }
            if (v.z > BAR) { int p = atomicAdd(&s_cnt, 1); if (p < CAP) cand[p] = mk_key(v.z, bi + 2); }
            if (v.w > BAR) { int p = atomicAdd(&s_cnt, 1); if (p < CAP) cand[p] = mk_key(v.w, bi + 3); }
        }
    }
    __syncthreads();
    const int N = s_cnt;

    if (N >= KSEL && N <= CAP) {
        // ---- common path: histogram-prune candidates, then rank-select top-K ----
        hist[tid] = 0;
        __syncthreads();
        for (int c = tid; c < N; c += NT) {
            unsigned bits = (unsigned)(cand[c] >> 32);
            unsigned b16 = (bits >> 16) - 0x4000u;   // bits >= 0x40200000 since v > 2.5
            if (b16 > 255u) b16 = 255u;              // saturate (keeps monotonicity)
            atomicAdd(&hist[b16], 1u);
        }
        __syncthreads();
        // single-wave barrier-free suffix scan: lane owns bins [4l, 4l+3]
        if (tid < 64) {
            const int lane = tid;
            const unsigned h0 = hist[4 * lane + 0], h1 = hist[4 * lane + 1];
            const unsigned h2 = hist[4 * lane + 2], h3 = hist[4 * lane + 3];
            const unsigned s3 = h3, s2 = h2 + s3, s1 = h1 + s2, s0 = h0 + s1;
            unsigned acc = s0;
#pragma unroll
            for (int off = 1; off < 64; off <<= 1) {
                unsigned o = __shfl_down(acc, off, 64);
                if (lane + off < 64) acc += o;
            }
            const unsigned above = acc - s0;        // sum over lanes > lane
            const unsigned suf0 = above + s0, suf1 = above + s1;
            const unsigned suf2 = above + s2, suf3 = above + s3;
            unsigned nxt = __shfl_down(suf0, 1, 64);
            const unsigned suf4 = (lane == 63) ? 0u : nxt;
            if (suf0 >= KSEL && suf1 < KSEL) s_bstar = 4 * lane + 0;
            if (suf1 >= KSEL && suf2 < KSEL) s_bstar = 4 * lane + 1;
            if (suf2 >= KSEL && suf3 < KSEL) s_bstar = 4 * lane + 2;
            if (suf3 >= KSEL && suf4 < KSEL) s_bstar = 4 * lane + 3;
        }
        __syncthreads();
        const int bstar = s_bstar;
        for (int c = tid; c < N; c += NT) {
            const unsigned long long kc = cand[c];
            unsigned bits = (unsigned)(kc >> 32);
            unsigned b16 = (bits >> 16) - 0x4000u;
            if (b16 > 255u) b16 = 255u;
            if ((int)b16 >= bstar) { int p = atomicAdd(&s_rcnt, 1); if (p < REF_CAP) refbuf[p] = kc; }
        }
        __syncthreads();
        const int M = s_rcnt;
        if (M <= REF_CAP) {
            for (int c = tid; c < M; c += NT) {
                const unsigned long long kc = refbuf[c];
                int rank = 0;
                for (int j = 0; j < M; ++j) rank += (refbuf[j] > kc) ? 1 : 0;
                if (rank < KSEL)
                    outr[0xFFFF - (int)(kc & 0xFFFFu)] = __uint_as_float((unsigned)(kc >> 32));
            }
        } else {
            // refine overflow (mass ties) — exact rank over full candidate list
            for (int c = tid; c < N; c += NT) {
                const unsigned long long kc = cand[c];
                int rank = 0;
                for (int j = 0; j < N; ++j) rank += (cand[j] > kc) ? 1 : 0;
                if (rank < KSEL)
                    outr[0xFFFF - (int)(kc & 0xFFFFu)] = __uint_as_float((unsigned)(kc >> 32));
            }
        }
        return;
    }

    // ---- exact fallback (should not trigger on N(0,1) data): radix select ----
    // Finds bit-threshold thr such that count{x>0, bits>=thr} in [K, CAP]
    // (or thr=1 if fewer than K positives), re-reading the row.
    unsigned pref = 0, thr = 1;
    int need = KSEL, above = 0;
    for (int s = 24; s >= 0; s -= 8) {
        __syncthreads();
        hist[tid] = 0;
        __syncthreads();
        for (int i = tid; i < COLS; i += NT) {
            float v = xr[i];
            if (v > 0.f) {
                unsigned bits = __float_as_uint(v);
                if (s == 24 || (bits >> (s + 8)) == pref)
                    atomicAdd(&hist[(bits >> s) & 255u], 1u);
            }
        }
        __syncthreads();
        if (tid == 0) {
            int cum = 0, b = 255;
            for (; b >= 0; --b) { if (cum + (int)hist[b] >= need) break; cum += (int)hist[b]; }
            s_bstar = b; s_cum = cum;
        }
        __syncthreads();
        const int b = s_bstar, cum = s_cum;
        if (b < 0) { thr = 1; break; }    // fewer than K positives: take all positives
        above += cum;
        need -= cum;
        pref = (pref << 8) | (unsigned)b;
        thr = pref << s;
        const int total = above + (int)hist[b];
        if (total <= CAP || s == 0) break;
    }
    __syncthreads();
    if (tid == 0) s_cnt = 0;
    __syncthreads();
    for (int i = tid; i < COLS; i += NT) {
        float v = xr[i];
        if (v > 0.f) {
            unsigned bits = __float_as_uint(v);
            if (bits >= thr) {
                int p = atomicAdd(&s_cnt, 1);
                if (p < CAP) cand[p] = ((unsigned long long)bits << 32) | (unsigned)(0xFFFF - i);
            }
        }
    }
    __syncthreads();
    const int M2 = min(s_cnt, CAP);
    for (int c = tid; c < M2; c += NT) {
        const unsigned long long kc = cand[c];
        int rank = 0;
        for (int j = 0; j < M2; ++j) rank += (cand[j] > kc) ? 1 : 0;
        if (rank < KSEL)
            outr[0xFFFF - (int)(kc & 0xFFFFu)] = __uint_as_float((unsigned)(kc >> 32));
    }
}

extern "C" void kernel_launch(void* const* d_in, const int* in_sizes, int n_in,
                              void* d_out, int out_size, void* d_ws, size_t ws_size,
                              hipStream_t stream) {
    const float* x = (const float*)d_in[0];
    float* out = (float*)d_out;
    const int rows = in_sizes[0] / COLS;
    hipLaunchKernelGGL(topk_scatter_kernel, dim3(rows), dim3(NT), 0, stream, x, out);
}

// Round 10
// 220.037 us; speedup vs baseline: 1.5072x; 1.0251x over previous
//
#include <hip/hip_runtime.h>

#define COLS    32768
#define KSEL    32
#define CAP     1024      // candidate buffer (expected ~203 hits/row at BAR=2.5, 57 sigma margin)
#define REF_CAP 256       // refined buffer after histogram prune (expected ~34)
#define NT      256
#define BAR     2.5f

typedef float f32x4 __attribute__((ext_vector_type(4)));

// key = (float_bits << 32) | (0xFFFF - idx)
// positive float bits are monotonic in value; low 16 bits break ties so that
// larger key == (larger value, or equal value with smaller index) — matching
// jax.lax.top_k tie order. All keys distinct since idx distinct.
__device__ __forceinline__ unsigned long long mk_key(float v, int idx) {
    return ((unsigned long long)__float_as_uint(v) << 32) | (unsigned)(0xFFFF - idx);
}

__global__ __launch_bounds__(NT) void topk_scatter_kernel(const float* __restrict__ x,
                                                          float* __restrict__ out) {
    __shared__ unsigned long long cand[CAP];
    __shared__ unsigned long long refbuf[REF_CAP];
    __shared__ unsigned hist[256];
    __shared__ unsigned suf[256];
    __shared__ int s_cnt, s_bstar, s_rcnt, s_cum;

    const int tid = threadIdx.x;
    const int lane = tid & 63;
    const size_t row = blockIdx.x;
    const float* __restrict__ xr = x + row * COLS;
    float* __restrict__ outr = out + row * COLS;

    if (tid == 0) { s_cnt = 0; s_rcnt = 0; }
    __syncthreads();

    // ---- Pass 1: stream row (nt-read x, nt-write zeros, wave-aggregated candidate push) ----
    const f32x4* __restrict__ xr4 = (const f32x4*)xr;
    f32x4* __restrict__ our4 = (f32x4*)outr;

#pragma unroll 4
    for (int i = 0; i < COLS / 4 / NT; ++i) {
        const int e = i * NT + tid;
        f32x4 v = __builtin_nontemporal_load(xr4 + e);
        f32x4 z = 0;
        __builtin_nontemporal_store(z, our4 + e);

        const bool p0 = v.x > BAR, p1 = v.y > BAR, p2 = v.z > BAR, p3 = v.w > BAR;
        const unsigned long long m0 = __ballot(p0), m1 = __ballot(p1),
                                 m2 = __ballot(p2), m3 = __ballot(p3);
        const int c0 = __popcll(m0), c1 = __popcll(m1), c2 = __popcll(m2), c3 = __popcll(m3);
        const int tot = c0 + c1 + c2 + c3;
        int base = 0;
        if (lane == 0 && tot) base = atomicAdd(&s_cnt, tot);
        base = __shfl(base, 0, 64);
        const unsigned long long lt = (1ull << lane) - 1;
        const int bi = e * 4;
        if (p0) { int p = base + __popcll(m0 & lt);                if (p < CAP) cand[p] = mk_key(v.x, bi + 0); }
        if (p1) { int p = base + c0 + __popcll(m1 & lt);           if (p < CAP) cand[p] = mk_key(v.y, bi + 1); }
        if (p2) { int p = base + c0 + c1 + __popcll(m2 & lt);      if (p < CAP) cand[p] = mk_key(v.z, bi + 2); }
        if (p3) { int p = base + c0 + c1 + c2 + __popcll(m3 & lt); if (p < CAP) cand[p] = mk_key(v.w, bi + 3); }
    }
    __syncthreads();
    const int N = s_cnt;

    if (N >= KSEL && N <= CAP) {
        // ---- common path: histogram-prune candidates, then rank-select top-K ----
        hist[tid] = 0;
        __syncthreads();
        for (int c = tid; c < N; c += NT) {
            unsigned bits = (unsigned)(cand[c] >> 32);
            unsigned b16 = (bits >> 16) - 0x4000u;   // bits >= 0x40200000 since v > 2.5
            if (b16 > 255u) b16 = 255u;              // saturate (keeps monotonicity)
            atomicAdd(&hist[b16], 1u);
        }
        __syncthreads();
        // parallel suffix-scan over 256 bins: suf[b] = sum_{j>=b} hist[j]
        suf[tid] = hist[tid];
        __syncthreads();
#pragma unroll
        for (int off = 1; off < 256; off <<= 1) {
            unsigned add = (tid + off < 256) ? suf[tid + off] : 0u;
            __syncthreads();
            suf[tid] += add;
            __syncthreads();
        }
        if (suf[tid] >= KSEL && (tid == 255 || suf[tid + 1] < KSEL)) s_bstar = tid;
        __syncthreads();
        const int bstar = s_bstar;
        for (int c = tid; c < N; c += NT) {
            const unsigned long long kc = cand[c];
            unsigned bits = (unsigned)(kc >> 32);
            unsigned b16 = (bits >> 16) - 0x4000u;
            if (b16 > 255u) b16 = 255u;
            if ((int)b16 >= bstar) { int p = atomicAdd(&s_rcnt, 1); if (p < REF_CAP) refbuf[p] = kc; }
        }
        __syncthreads();
        const int M = s_rcnt;
        if (M <= REF_CAP) {
            for (int c = tid; c < M; c += NT) {
                const unsigned long long kc = refbuf[c];
                int rank = 0;
                for (int j = 0; j < M; ++j) rank += (refbuf[j] > kc) ? 1 : 0;
                if (rank < KSEL)
                    outr[0xFFFF - (int)(kc & 0xFFFFu)] = __uint_as_float((unsigned)(kc >> 32));
            }
        } else {
            // refine overflow (mass ties) — exact rank over full candidate list
            for (int c = tid; c < N; c += NT) {
                const unsigned long long kc = cand[c];
                int rank = 0;
                for (int j = 0; j < N; ++j) rank += (cand[j] > kc) ? 1 : 0;
                if (rank < KSEL)
                    outr[0xFFFF - (int)(kc & 0xFFFFu)] = __uint_as_float((unsigned)(kc >> 32));
            }
        }
        return;
    }

    // ---- exact fallback (should not trigger on N(0,1) data): radix select ----
    // Finds bit-threshold thr such that count{x>0, bits>=thr} in [K, CAP]
    // (or thr=1 if fewer than K positives), re-reading the row.
    unsigned pref = 0, thr = 1;
    int need = KSEL, above = 0;
    for (int s = 24; s >= 0; s -= 8) {
        __syncthreads();
        hist[tid] = 0;
        __syncthreads();
        for (int i = tid; i < COLS; i += NT) {
            float v = xr[i];
            if (v > 0.f) {
                unsigned bits = __float_as_uint(v);
                if (s == 24 || (bits >> (s + 8)) == pref)
                    atomicAdd(&hist[(bits >> s) & 255u], 1u);
            }
        }
        __syncthreads();
        if (tid == 0) {
            int cum = 0, b = 255;
            for (; b >= 0; --b) { if (cum + (int)hist[b] >= need) break; cum += (int)hist[b]; }
            s_bstar = b; s_cum = cum;
        }
        __syncthreads();
        const int b = s_bstar, cum = s_cum;
        if (b < 0) { thr = 1; break; }    // fewer than K positives: take all positives
        above += cum;
        need -= cum;
        pref = (pref << 8) | (unsigned)b;
        thr = pref << s;
        const int total = above + (int)hist[b];
        if (total <= CAP || s == 0) break;
    }
    __syncthreads();
    if (tid == 0) s_cnt = 0;
    __syncthreads();
    for (int i = tid; i < COLS; i += NT) {
        float v = xr[i];
        if (v > 0.f) {
            unsigned bits = __float_as_uint(v);
            if (bits >= thr) {
                int p = atomicAdd(&s_cnt, 1);
                if (p < CAP) cand[p] = ((unsigned long long)bits << 32) | (unsigned)(0xFFFF - i);
            }
        }
    }
    __syncthreads();
    const int M2 = min(s_cnt, CAP);
    for (int c = tid; c < M2; c += NT) {
        const unsigned long long kc = cand[c];
        int rank = 0;
        for (int j = 0; j < M2; ++j) rank += (cand[j] > kc) ? 1 : 0;
        if (rank < KSEL)
            outr[0xFFFF - (int)(kc & 0xFFFFu)] = __uint_as_float((unsigned)(kc >> 32));
    }
}

extern "C" void kernel_launch(void* const* d_in, const int* in_sizes, int n_in,
                              void* d_out, int out_size, void* d_ws, size_t ws_size,
                              hipStream_t stream) {
    const float* x = (const float*)d_in[0];
    float* out = (float*)d_out;
    const int rows = in_sizes[0] / COLS;
    hipLaunchKernelGGL(topk_scatter_kernel, dim3(rows), dim3(NT), 0, stream, x, out);
}